// Round 9
// baseline (451.850 us; speedup 1.0000x reference)
//
#include <hip/hip_runtime.h>
#include <math.h>

typedef unsigned int u32;
typedef unsigned long long u64;

#define NANCH   36864
#define PRE     6000
#define POST    2000
#define NWORDS  94        // ceil(6000/64)
#define NSTEPS  47        // 2 words per step

// ---------------- workspace layout (bytes) ----------------
#define OFF_PROPS   ((size_t)0)                    // 36864 * 16 = 589824
#define OFF_SV      ((size_t)589824)               // 36864 * 8  = 294912 -> end 884736
#define OFF_SORTED  ((size_t)884736)               // 6016 * 8   = 48128  -> end 932864
#define OFF_SEL     ((size_t)932864)               // 36864 * 8  = 294912 (fallback-sized) -> end 1227776
#define OFF_MASK    ((size_t)1227776)              // 6000 * 94 * 8 = 4512000 -> end 5739776
#define OFF_CTRL    ((size_t)5739776)              // 256 B
#define OFF_H1      ((size_t)5740032)              // 1025*4 -> pad 4352 -> end 5744384
#define OFF_INVALW  ((size_t)5744384)              // 94*8 -> pad 768 -> end 5745152
#define ZERO_BYTES  ((size_t)(256 + 4352 + 768))   // ctrl + h1 + invalw

// base anchors for base_size=16, ratios(0.5,1,2), scales(8,16,32) — np.round (banker's) applied
__device__ __constant__ float BA[9][4] = {
  {-84.f,-40.f,99.f,55.f},   {-176.f,-88.f,191.f,103.f}, {-360.f,-184.f,375.f,199.f},
  {-56.f,-56.f,71.f,71.f},   {-120.f,-120.f,135.f,135.f},{-248.f,-248.f,263.f,263.f},
  {-36.f,-80.f,51.f,95.f},   {-80.f,-168.f,95.f,183.f},  {-168.f,-344.f,183.f,359.f}};

// bin over key bits [31:13]: 1024 bins cover scores [0.5,1) exactly (monotone in key);
// bin 0 = everything below (incl. invalid key==0). Selection stays EXACT: we take the
// whole union of bins >= chosen and rank it all-pairs (keys are distinct).
__device__ __forceinline__ u32 key_bin(u32 key) {
  if (key < 0xBF000000u) return 0u;
  u32 b = ((key >> 13) - 0x5F800u) + 1u;
  return b > 1024u ? 1024u : b;
}

// ---------------- 1) decode (+ fused 1024-bin histogram; bin 0 not counted) ----------------
__global__ void decode_k(const float* __restrict__ deltas, const float* __restrict__ scores,
                         const int* __restrict__ imw_p, const int* __restrict__ imh_p,
                         float4* __restrict__ props, u64* __restrict__ sortvals,
                         u32* __restrict__ h1) {
  #pragma clang fp contract(off)
  int i = blockIdx.x * 256 + threadIdx.x;
  if (i >= NANCH) return;
  int a = i % 9;
  int pix = i / 9;
  int x = pix & 63, y = pix >> 6;

  float sc = scores[(9 + a) * 4096 + pix];
  float d0 = deltas[(a * 4 + 0) * 4096 + pix];
  float d1 = deltas[(a * 4 + 1) * 4096 + pix];
  float d2 = deltas[(a * 4 + 2) * 4096 + pix];
  float d3 = deltas[(a * 4 + 3) * 4096 + pix];

  float gx = (float)(x * 16), gy = (float)(y * 16);
  float ax1 = gx + BA[a][0], ay1 = gy + BA[a][1];
  float ax2 = gx + BA[a][2], ay2 = gy + BA[a][3];
  float aw = ax2 - ax1 + 1.0f, ah = ay2 - ay1 + 1.0f;
  float acx = ax1 + 0.5f * aw, acy = ay1 + 0.5f * ah;

  float pcx = d0 * aw + acx;
  float pcy = d1 * ah + acy;
  float pw = (float)exp((double)d2) * aw;   // f64 exp -> correctly-rounded f32
  float ph = (float)exp((double)d3) * ah;

  float imw1 = (float)imw_p[0] - 1.0f, imh1 = (float)imh_p[0] - 1.0f;
  float x1 = fminf(fmaxf(pcx - 0.5f * pw, 0.0f), imw1);
  float y1 = fminf(fmaxf(pcy - 0.5f * ph, 0.0f), imh1);
  float x2 = fminf(fmaxf(pcx + 0.5f * pw, 0.0f), imw1);
  float y2 = fminf(fmaxf(pcy + 0.5f * ph, 0.0f), imh1);
  props[i] = make_float4(x1, y1, x2, y2);

  float thresh = 16.0f * ((float)imh_p[0] / (float)imw_p[0]);
  bool keep = (x2 - x1 + 1.0f >= thresh) && (y2 - y1 + 1.0f >= thresh);
  u32 key = keep ? (__float_as_uint(sc) | 0x80000000u) : 0u;  // scores >= 0
  sortvals[i] = ((u64)key << 32) | (u64)(0xFFFFFFFFu - (u32)i); // distinct; desc order == top_k order
  u32 bin = key_bin(key);
  if (bin) atomicAdd(&h1[bin], 1u);
}

// ---------------- 2+3) per-block chosen bin + compact union ----------------
// chosen = largest c>=1 with suffix(c) >= PRE (else 0); computed redundantly per block
// from the completed histogram (identical result everywhere), then compact in-place.
__global__ void compact_k(const u32* __restrict__ h1, const u64* __restrict__ sv,
                          u32* __restrict__ ctrl, u64* __restrict__ sel) {
  __shared__ u32 Lchosen;
  int t = threadIdx.x;
  if (t < 64) {
    int l = t;
    u32 loc[16], suf[16];
    #pragma unroll
    for (int k = 0; k < 16; ++k) loc[k] = h1[1 + l * 16 + k];
    u32 acc = 0;
    #pragma unroll
    for (int k = 15; k >= 0; --k) { acc += loc[k]; suf[k] = acc; }
    u32 sfx = acc;
    for (int off = 1; off < 64; off <<= 1) {
      u32 o = __shfl_down(sfx, off);
      if (l + off < 64) sfx += o;
    }
    u32 S_above = sfx - acc;
    u64 mball = __ballot(suf[0] + S_above >= (u32)PRE);
    if (mball == 0ULL) {
      if (l == 0) Lchosen = 0u;          // fallback: union = everything
    } else {
      int L = 63 - __builtin_clzll(mball);
      if (l == L) {
        int kk = 0;
        for (int k = 15; k >= 0; --k)
          if (suf[k] + S_above >= (u32)PRE) { kk = k; break; }
        Lchosen = (u32)(1 + 16 * L + kk);
      }
    }
  }
  __syncthreads();
  u32 chosen = Lchosen;
  int i = blockIdx.x * 256 + t;          // 144*256 == NANCH exactly
  u64 v = sv[i];
  if (key_bin((u32)(v >> 32)) >= chosen) {
    u32 p = atomicAdd(&ctrl[6], 1u);
    sel[p] = v;
  }
}

// ---------------- 4) all-pairs rank of the union -> exact descending sort of top-PRE ----------
__global__ void rank_k(const u64* __restrict__ sel, const u32* __restrict__ ctrl,
                       u64* __restrict__ sorted, u64* __restrict__ invalw) {
  __shared__ u64 sj[256];
  u32 n = ctrl[6];
  int i = blockIdx.x * 256 + threadIdx.x;
  if ((u32)(blockIdx.x * 256) >= n) return;       // uniform per block
  u64 vi = ((u32)i < n) ? sel[i] : 0ULL;
  u32 cnt = 0;
  for (u32 jb = 0; jb < n; jb += 256) {
    __syncthreads();
    if (jb + threadIdx.x < n) sj[threadIdx.x] = sel[jb + threadIdx.x];
    __syncthreads();
    u32 m = min(256u, n - jb);
    #pragma unroll 8
    for (u32 j = 0; j < m; ++j) cnt += (u32)(sj[j] > vi);
  }
  if ((u32)i < n && cnt < (u32)PRE) {
    sorted[cnt] = vi;
    if ((u32)(vi >> 32) == 0u)
      atomicOr((unsigned long long*)&invalw[cnt >> 6], 1ULL << (cnt & 63));
  }
}

// ---------------- 5) suppression bitmask: upper-triangle 64x64 tiles (inline gather) --------
__global__ void mask_k(const u64* __restrict__ sorted, const float4* __restrict__ props,
                       u64* __restrict__ mask) {
  #pragma clang fp contract(off)
  __shared__ float4 cb[64];
  int jb = blockIdx.x;
  if (jb < (int)blockIdx.y) return;   // only w >= row-block is ever read
  int i = blockIdx.y * 64 + threadIdx.x;
  int jj = jb * 64 + threadIdx.x;
  float4 cc = make_float4(0.f, 0.f, 0.f, 0.f);
  if (jj < PRE) {
    u64 v = sorted[jj];
    cc = props[0xFFFFu - ((u32)v & 0xFFFFu)];
  }
  cb[threadIdx.x] = cc;
  __syncthreads();
  if (i >= PRE) return;
  u64 vi = sorted[i];
  float4 b = props[0xFFFFu - ((u32)vi & 0xFFFFu)];
  float ai = (b.z - b.x + 1.0f) * (b.w - b.y + 1.0f);
  u64 bits = 0ULL;
  int jmax = min(64, PRE - jb * 64);
  for (int j = 0; j < jmax; ++j) {
    float4 c = cb[j];
    float aj = (c.z - c.x + 1.0f) * (c.w - c.y + 1.0f);
    float iw = fmaxf(fminf(b.z, c.z) - fmaxf(b.x, c.x) + 1.0f, 0.0f);
    float ih = fmaxf(fminf(b.w, c.w) - fmaxf(b.y, c.y) + 1.0f, 0.0f);
    float inter = iw * ih;
    float iou = inter / (ai + aj - inter);
    bits |= ((u64)(iou > 0.7f)) << j;
  }
  mask[(size_t)i * NWORDS + jb] = bits;
}

// ---------------- 6) 2-word greedy scan (R2 logic, scalar buffers) + fused scatter ----------
// Buffers are 32 NAMED u64 scalars (no arrays!) — R2/R4's arrays were demoted to scratch
// (localMem), causing 168 KB of scratch traffic and a 2.4x regression at VGPR_Count=64.
// __launch_bounds__(1024, 4): 16 waves/CU -> VGPR budget ~128; expect ~80-110 allocated.
__device__ __forceinline__ void barrier_nodrain() {
  __builtin_amdgcn_sched_barrier(0);
  asm volatile("s_waitcnt lgkmcnt(0)" ::: "memory");
  __builtin_amdgcn_s_barrier();
  __builtin_amdgcn_sched_barrier(0);
}

__device__ __forceinline__ u64 rl64(u64 v, int lane) {
  u32 lo = (u32)__builtin_amdgcn_readlane((int)(u32)v, lane);
  u32 hi = (u32)__builtin_amdgcn_readlane((int)(u32)(v >> 32), lane);
  return ((u64)hi << 32) | (u64)lo;
}
__device__ __forceinline__ u64 rfl64(u64 v) {
  u32 lo = (u32)__builtin_amdgcn_readfirstlane((int)(u32)v);
  u32 hi = (u32)__builtin_amdgcn_readfirstlane((int)(u32)(v >> 32));
  return ((u64)hi << 32) | (u64)lo;
}

#define DECL8(P) u64 P##0 = 0, P##1 = 0, P##2 = 0, P##3 = 0, P##4 = 0, P##5 = 0, P##6 = 0, P##7 = 0;

#define LD2(BA, BB, j) { \
    bool okA_ = (w >= Ai_) && !((stA_ >> (g * 8 + j)) & 1ULL); \
    BA##j = okA_ ? pA_[(size_t)j * NWORDS] : 0ULL; \
    bool okB_ = (w >= Bi_) && (rB_ + j < PRE) && !((stB_ >> (g * 8 + j)) & 1ULL); \
    BB##j = okB_ ? pB_[(size_t)j * NWORDS] : 0ULL; }

#define ISSUE2(ss, BA, BB) \
  if ((ss) < NSTEPS && loader) { \
    const int Ai_ = 2 * (ss), Bi_ = Ai_ + 1; \
    u64 stA_ = Lrem[Ai_], stB_ = Lrem[Bi_]; \
    const int rB_ = Bi_ * 64 + g * 8; \
    const u64* pA_ = mask + (size_t)(Ai_ * 64 + g * 8) * NWORDS + w; \
    const u64* pB_ = mask + (size_t)rB_ * NWORDS + w; \
    LD2(BA, BB, 0) LD2(BA, BB, 1) LD2(BA, BB, 2) LD2(BA, BB, 3) \
    LD2(BA, BB, 4) LD2(BA, BB, 5) LD2(BA, BB, 6) LD2(BA, BB, 7) \
  }

#define STAA(BA, j) LdAA[g * 8 + j] = BA##j;
#define STBB(BA, BB, j) { LdAB[g * 8 + j] = BA##j; LdBB[g * 8 + j] = BB##j; }
#define FOLD2(BA, BB, j) { \
    u64 mA_ = 0ULL - ((kA_ >> (base_ + j)) & 1ULL); \
    u64 mB_ = 0ULL - ((kB_ >> (base_ + j)) & 1ULL); \
    rv |= (mA_ & BA##j) | (mB_ & BB##j); }

#define STEP2(ss, BA, BB) { \
    const int A_ = 2 * (ss), B_ = A_ + 1; \
    if (w == A_ || w == B_) {            /* final publish for words A,B */ \
      atomicOr((u32*)&Lrem[w], (u32)rv); \
      atomicOr(((u32*)&Lrem[w]) + 1, (u32)(rv >> 32)); \
    } \
    if (w == A_) { STAA(BA,0) STAA(BA,1) STAA(BA,2) STAA(BA,3) STAA(BA,4) STAA(BA,5) STAA(BA,6) STAA(BA,7) } \
    if (w == B_) { STBB(BA,BB,0) STBB(BA,BB,1) STBB(BA,BB,2) STBB(BA,BB,3) \
                   STBB(BA,BB,4) STBB(BA,BB,5) STBB(BA,BB,6) STBB(BA,BB,7) } \
    { const int A2_ = A_ + 4;            /* early partial publish for step ss+2 */ \
      if (A2_ < NWORDS && (w == A2_ || w == A2_ + 1)) { \
        atomicOr((u32*)&Lrem[w], (u32)rv); \
        atomicOr(((u32*)&Lrem[w]) + 1, (u32)(rv >> 32)); \
      } } \
    barrier_nodrain();                   /* X: diag + Lrem finals visible */ \
    if (t < 64) { \
      u64 dAA = LdAA[t], dAB = LdAB[t], dBB = LdBB[t]; \
      u64 availA = ~rfl64(Lrem[A_]); \
      u64 kbA = 0, supB = 0; \
      while (availA) { \
        int i_ = __builtin_ctzll(availA); \
        kbA |= 1ULL << i_; \
        u64 rA1_ = rl64(dAA, i_); \
        supB |= rl64(dAB, i_); \
        availA &= ~rA1_ & ~((2ULL << i_) - 1ULL); /* 2<<63 wraps to 0 -> ~(-1)=0 */ \
      } \
      u64 availB = ~(rfl64(Lrem[B_]) | supB); \
      u64 kbB = 0; \
      while (availB) { \
        int i_ = __builtin_ctzll(availB); \
        kbB |= 1ULL << i_; \
        u64 rB1_ = rl64(dBB, i_); \
        availB &= ~rB1_ & ~((2ULL << i_) - 1ULL); \
      } \
      if (t == 0) { \
        Lkw[A_] = kbA; \
        LkA = kbA; \
        kept += (int)__popcll(kbA); \
        if (kept >= POST) { Lstop = 1; Llast = A_; LkB = 0ULL; } \
        else { \
          Lkw[B_] = kbB; \
          LkB = kbB; \
          kept += (int)__popcll(kbB); \
          if (kept >= POST) { Lstop = 1; Llast = B_; } \
        } \
      } \
    } \
    barrier_nodrain();                   /* Y: kb + stop visible */ \
    { \
      u64 kA_ = LkA, kB_ = LkB; \
      const int base_ = g * 8; \
      FOLD2(BA,BB,0) FOLD2(BA,BB,1) FOLD2(BA,BB,2) FOLD2(BA,BB,3) \
      FOLD2(BA,BB,4) FOLD2(BA,BB,5) FOLD2(BA,BB,6) FOLD2(BA,BB,7) \
    } \
    ISSUE2((ss) + 2, BA, BB)             /* refill this buffer for step ss+2 */ \
    if (Lstop) break; }

__global__ void __launch_bounds__(1024, 4) nms_scan_k(const u64* __restrict__ mask,
                                                      const u64* __restrict__ invalw,
                                                      const u64* __restrict__ sorted,
                                                      const float4* __restrict__ props,
                                                      float* __restrict__ out) {
  __shared__ u64 Lrem[NWORDS];
  __shared__ u64 Lkw[NWORDS];
  __shared__ u64 LdAA[64];            // rows of word A @ col-word A
  __shared__ u64 LdAB[64];            // rows of word A @ col-word B
  __shared__ u64 LdBB[64];            // rows of word B @ col-word B
  __shared__ u64 LkA, LkB;
  __shared__ int Lstop;
  __shared__ int Llast;
  __shared__ u32 prew[NWORDS];
  const int t = threadIdx.x;
  const int g = t >> 7;                 // 8 groups of 128 threads
  const int w = t & 127;                // column word owned (if < 94)
  const bool loader = (w < NWORDS);
  if (t < NWORDS) Lrem[t] = invalw[t];
  if (t == 0) { Lstop = 0; Llast = NWORDS - 1; }
  for (int i = t; i < 12000; i += 1024) out[i] = 0.0f;   // d_out zero (fused outscatter)
  u64 rv = 0;                           // group-partial remv for column w
  DECL8(p0a) DECL8(p0b) DECL8(p1a) DECL8(p1b)            // 32 named u64 buffer scalars
  int kept = 0;
  __syncthreads();                      // Lrem init visible for predicated ISSUE

  ISSUE2(0, p0a, p0b)
  ISSUE2(1, p1a, p1b)
  for (int s = 0; s < NSTEPS; s += 2) {
    STEP2(s, p0a, p0b)
    if (s + 1 < NSTEPS) STEP2(s + 1, p1a, p1b)
  }

  __syncthreads();                      // full drain: Llast final, out-zero ordered
  int last = Llast;
  for (int w2 = t; w2 < NWORDS; w2 += 1024)
    if (w2 > last) Lkw[w2] = 0ULL;
  __syncthreads();

  // fused outscatter: prefix + scatter from LDS keep words
  if (t == 0) {
    u32 run = 0;
    for (int w2 = 0; w2 < NWORDS; ++w2) { prew[w2] = run; run += (u32)__popcll(Lkw[w2]); }
  }
  __syncthreads();
  for (int i = t; i < PRE; i += 1024) {
    int w2 = i >> 6;
    u64 word = Lkw[w2];
    if ((word >> (i & 63)) & 1ULL) {
      u32 rank = prew[w2] + (u32)__popcll(word & ((1ULL << (i & 63)) - 1ULL));
      if (rank < POST) {
        u64 v = sorted[i];
        float4 b = props[0xFFFFu - ((u32)v & 0xFFFFu)];
        out[rank * 5 + 1] = b.x;
        out[rank * 5 + 2] = b.y;
        out[rank * 5 + 3] = b.z;
        out[rank * 5 + 4] = b.w;
        out[10000 + rank] = __uint_as_float((u32)(v >> 32) & 0x7FFFFFFFu);  // col 0 stays 0
      }
    }
  }
}

extern "C" void kernel_launch(void* const* d_in, const int* in_sizes, int n_in,
                              void* d_out, int out_size, void* d_ws, size_t ws_size,
                              hipStream_t stream) {
  const float* deltas = (const float*)d_in[0];
  const float* scores = (const float*)d_in[1];
  const int* imw = (const int*)d_in[2];
  const int* imh = (const int*)d_in[3];
  char* ws = (char*)d_ws;

  float4* props   = (float4*)(ws + OFF_PROPS);
  u64*    svals   = (u64*)(ws + OFF_SV);
  u64*    sorted  = (u64*)(ws + OFF_SORTED);
  u64*    sel     = (u64*)(ws + OFF_SEL);
  u64*    maskb   = (u64*)(ws + OFF_MASK);
  u32*    ctrl    = (u32*)(ws + OFF_CTRL);
  u32*    h1      = (u32*)(ws + OFF_H1);
  u64*    invalw  = (u64*)(ws + OFF_INVALW);

  hipMemsetAsync(ws + OFF_CTRL, 0, ZERO_BYTES, stream);   // ctrl + h1 + invalw

  decode_k<<<144, 256, 0, stream>>>(deltas, scores, imw, imh, props, svals, h1);
  compact_k<<<144, 256, 0, stream>>>(h1, svals, ctrl, sel);
  rank_k<<<144, 256, 0, stream>>>(sel, ctrl, sorted, invalw);

  dim3 mgrid(NWORDS, NWORDS);
  mask_k<<<mgrid, 64, 0, stream>>>(sorted, props, maskb);

  nms_scan_k<<<1, 1024, 0, stream>>>(maskb, invalw, sorted, props, (float*)d_out);
}